// Round 3
// baseline (593.416 us; speedup 1.0000x reference)
//
#include <hip/hip_runtime.h>

#define Z_TOTAL 32768
#define ZTL ((size_t)Z_TOTAL)
#define THREADS 256

// y1[a,c,z] = sum_b x1[a,b,z] * x0[b,c,z]
// y2[a,d,z] = sum_c y1[a,c,z] * x2[c,d,z]
//
// Block = 32 z-lanes x 8 a-groups (Ar=2) -> 16 a-rows (one a-half).
// 16 pipelined rounds (8 x0-eighths, 8 x2-eighths), each staging a
// 4-row x 32-col x 32-z tile (16 KB) into a ping-pong LDS pair.
// Round t: {issue gather t+1 -> regs | compute from buf[t&1] |
//           ds_write regs -> buf[(t+1)&1] | barrier}.
// HBM latency of the gather hides under the 256-FMA compute.
__global__ __launch_bounds__(THREADS, 3) void einnet_kernel(
    const float* __restrict__ x0,   // (b,c,Z)
    const float* __restrict__ x1,   // (a,b,Z)
    const float* __restrict__ x2,   // (c,d,Z)
    float* __restrict__ out)        // (a,d,Z)
{
    __shared__ float lds[8192];     // 2 x 16 KB ping-pong

    const int tid = threadIdx.x;
    const int bid = blockIdx.x;
    const int zc    = (bid >> 4) * 8 + (bid & 7);   // XCD-pair swizzle
    const int ahalf = (bid >> 3) & 1;
    const int z0 = zc * 32;
    const int zl = tid & 31;
    const int ag = tid >> 5;                         // 0..7
    const int a0 = ahalf * 16 + ag * 2;

    float y1[2][32];
    #pragma unroll
    for (int r = 0; r < 2; ++r)
        #pragma unroll
        for (int c = 0; c < 32; ++c) y1[r][c] = 0.f;

    float4 g[4];        // staged tile fragment (next round)
    float xv[2][4];     // x1 fragment (current round)
    float xn[2][4];     // x1 fragment (next round)

    // ---- prologue: gather x0 tile 0 + x1 tile 0, write buf0
    #pragma unroll
    for (int i = 0; i < 4; ++i) {
        const float* s = x0 + (size_t)(i * 32 + ag * 4) * ZTL + z0 + zl;
        g[i].x = s[0]; g[i].y = s[ZTL]; g[i].z = s[2 * ZTL]; g[i].w = s[3 * ZTL];
    }
    #pragma unroll
    for (int r = 0; r < 2; ++r)
        #pragma unroll
        for (int bl = 0; bl < 4; ++bl)
            xv[r][bl] = x1[(size_t)((a0 + r) * 32 + bl) * ZTL + z0 + zl];

    #pragma unroll
    for (int i = 0; i < 4; ++i)
        *reinterpret_cast<float4*>(&lds[((i * 8 + ag) * 32 + zl) * 4]) = g[i];
    __syncthreads();

    // ---- phase 1: 8 rounds over b-eighths
    #pragma unroll 1
    for (int t = 0; t < 8; ++t) {
        // issue next-tile gather (t=7 -> x2 tile 0, keeps pipeline full)
        const float* nsrc = (t < 7) ? (x0 + (size_t)(t + 1) * 128 * ZTL) : x2;
        #pragma unroll
        for (int i = 0; i < 4; ++i) {
            const float* s = nsrc + (size_t)(i * 32 + ag * 4) * ZTL + z0 + zl;
            g[i].x = s[0]; g[i].y = s[ZTL]; g[i].z = s[2 * ZTL]; g[i].w = s[3 * ZTL];
        }
        // next x1 fragment (t=7 wraps harmlessly; dead, DCE'd)
        const int tn = (t + 1) & 7;
        #pragma unroll
        for (int r = 0; r < 2; ++r)
            #pragma unroll
            for (int bl = 0; bl < 4; ++bl)
                xn[r][bl] = x1[(size_t)((a0 + r) * 32 + tn * 4 + bl) * ZTL + z0 + zl];

        // compute from current buffer
        const float* buf = &lds[(t & 1) * 4096];
        #pragma unroll
        for (int bl = 0; bl < 4; ++bl) {
            #pragma unroll
            for (int c4 = 0; c4 < 8; ++c4) {
                float4 s = *reinterpret_cast<const float4*>(
                    &buf[((bl * 8 + c4) * 32 + zl) * 4]);
                #pragma unroll
                for (int r = 0; r < 2; ++r) {
                    y1[r][c4 * 4 + 0] = fmaf(xv[r][bl], s.x, y1[r][c4 * 4 + 0]);
                    y1[r][c4 * 4 + 1] = fmaf(xv[r][bl], s.y, y1[r][c4 * 4 + 1]);
                    y1[r][c4 * 4 + 2] = fmaf(xv[r][bl], s.z, y1[r][c4 * 4 + 2]);
                    y1[r][c4 * 4 + 3] = fmaf(xv[r][bl], s.w, y1[r][c4 * 4 + 3]);
                }
            }
        }

        // write next tile into the other buffer, then one barrier
        float* wbuf = &lds[((t + 1) & 1) * 4096];
        #pragma unroll
        for (int i = 0; i < 4; ++i)
            *reinterpret_cast<float4*>(&wbuf[((i * 8 + ag) * 32 + zl) * 4]) = g[i];
        #pragma unroll
        for (int r = 0; r < 2; ++r)
            #pragma unroll
            for (int bl = 0; bl < 4; ++bl) xv[r][bl] = xn[r][bl];
        __syncthreads();
    }

    // ---- phase 2: 8 rounds over c-eighths (full unroll: static y1 index)
    float y2[2][32];
    #pragma unroll
    for (int r = 0; r < 2; ++r)
        #pragma unroll
        for (int d = 0; d < 32; ++d) y2[r][d] = 0.f;

    #pragma unroll
    for (int t = 0; t < 8; ++t) {
        if (t < 7) {
            const float* nsrc = x2 + (size_t)(t + 1) * 128 * ZTL;
            #pragma unroll
            for (int i = 0; i < 4; ++i) {
                const float* s = nsrc + (size_t)(i * 32 + ag * 4) * ZTL + z0 + zl;
                g[i].x = s[0]; g[i].y = s[ZTL]; g[i].z = s[2 * ZTL]; g[i].w = s[3 * ZTL];
            }
        }

        const float* buf = &lds[(t & 1) * 4096];
        #pragma unroll
        for (int cl = 0; cl < 4; ++cl) {
            #pragma unroll
            for (int d4 = 0; d4 < 8; ++d4) {
                float4 s = *reinterpret_cast<const float4*>(
                    &buf[((cl * 8 + d4) * 32 + zl) * 4]);
                #pragma unroll
                for (int r = 0; r < 2; ++r) {
                    const float w1 = y1[r][t * 4 + cl];
                    y2[r][d4 * 4 + 0] = fmaf(w1, s.x, y2[r][d4 * 4 + 0]);
                    y2[r][d4 * 4 + 1] = fmaf(w1, s.y, y2[r][d4 * 4 + 1]);
                    y2[r][d4 * 4 + 2] = fmaf(w1, s.z, y2[r][d4 * 4 + 2]);
                    y2[r][d4 * 4 + 3] = fmaf(w1, s.w, y2[r][d4 * 4 + 3]);
                }
            }
        }

        if (t < 7) {
            float* wbuf = &lds[((t + 1) & 1) * 4096];
            #pragma unroll
            for (int i = 0; i < 4; ++i)
                *reinterpret_cast<float4*>(&wbuf[((i * 8 + ag) * 32 + zl) * 4]) = g[i];
            __syncthreads();
        }
    }

    // ---- store: 128 B segments per (a,d) row
    #pragma unroll
    for (int r = 0; r < 2; ++r) {
        #pragma unroll
        for (int d = 0; d < 32; ++d)
            out[(size_t)((a0 + r) * 32 + d) * ZTL + z0 + zl] = y2[r][d];
    }
}

extern "C" void kernel_launch(void* const* d_in, const int* in_sizes, int n_in,
                              void* d_out, int out_size, void* d_ws, size_t ws_size,
                              hipStream_t stream) {
    const float* x0 = (const float*)d_in[0];  // (b,c,Z)
    const float* x1 = (const float*)d_in[1];  // (a,b,Z)
    const float* x2 = (const float*)d_in[2];  // (c,d,Z)
    float* out = (float*)d_out;

    dim3 grid(2048);   // 1024 z-chunks x 2 a-halves
    dim3 block(THREADS);
    hipLaunchKernelGGL(einnet_kernel, grid, block, 0, stream, x0, x1, x2, out);
}

// Round 4
// 485.893 us; speedup vs baseline: 1.2213x; 1.2213x over previous
//
#include <hip/hip_runtime.h>

#define ZT 32768
#define ZTL ((size_t)ZT)
#define THREADS 256

// y1[a,c,z] = sum_b x1[a,b,z] * x0[b,c,z]
// y2[a,d,z] = sum_c y1[a,c,z] * x2[c,d,z]
//
// Block = 32 z x 16 a-rows (one a-half), Ar=2 per thread. 16 rounds of 4-row
// contraction tiles, double-buffered. ALL staging via global_load_lds size=4
// with pre-swizzled per-lane global sources (LDS dest linear), so the LDS
// tile layout [row4][z32][4] supports ds_read_b128 in compute while staging
// costs ZERO registers. Counted vmcnt (24/16, never 0 mid-loop) keeps one
// full 24 KB tile in flight per block at all times -> HBM streams.

#define GLDS(src, dst) __builtin_amdgcn_global_load_lds( \
    (const __attribute__((address_space(1))) void*)(src), \
    (__attribute__((address_space(3))) void*)(dst), 4, 0, 0)

__global__ __launch_bounds__(THREADS, 2) void einnet_kernel(
    const float* __restrict__ x0,   // (b,c,Z)
    const float* __restrict__ x1,   // (a,b,Z)
    const float* __restrict__ x2,   // (c,d,Z)
    float* __restrict__ out)        // (a,d,Z)
{
    // per buffer: 4096 floats main tile (x0/x2) + 2048 floats x1 slice
    __shared__ float lds[12288];    // 48 KiB

    const int tid  = threadIdx.x;
    const int lane = tid & 63;
    const int wv   = tid >> 6;          // wave 0..3
    const int bid  = blockIdx.x;
    const int zc    = (bid >> 4) * 8 + (bid & 7);   // XCD-pair swizzle
    const int ahalf = (bid >> 3) & 1;
    const int z0 = zc * 32;
    const int zl = tid & 31;
    const int ag = tid >> 5;            // 0..7

    // pre-swizzled per-lane source offsets (floats)
    // main tile: LDS word j=(w*1024+i*64+lane): row=(4t+w)*32+(i>>1)*4+(lane&3), z=(i&1)*16+(lane>>2)
    const size_t inv0 = (size_t)(lane & 3) * ZTL + (size_t)(lane >> 2);
    // x1 slice: LDS word M=(w*512+i*64+lane): ar=w*4+(i>>1), bl=(i&1)*2+(lane>>5), z=lane&31
    const size_t inv1 = (size_t)(lane >> 5) * ZTL + (size_t)(lane & 31);

    // ---- stage issuers (uniform control flow; each wave stages its quarter)
    auto stageMain = [&](const float* mat, int tt, float* bb) {
        const float* mb = mat + (size_t)(tt * 128 + wv * 32) * ZTL + z0 + inv0;
        float* db = bb + wv * 1024;
        #pragma unroll
        for (int i = 0; i < 16; ++i)
            GLDS(mb + (size_t)((i >> 1) * 4) * ZTL + (i & 1) * 16, db + i * 64);
    };
    auto stageX1 = [&](int tt, float* bb) {
        const float* m1 = x1 + (size_t)((ahalf * 16 + wv * 4) * 32 + tt * 4) * ZTL + z0 + inv1;
        float* d1 = bb + 4096 + wv * 512;
        #pragma unroll
        for (int i = 0; i < 8; ++i)
            GLDS(m1 + (size_t)((i >> 1) * 32 + (i & 1) * 2) * ZTL, d1 + i * 64);
    };

    float y1[2][32];
    #pragma unroll
    for (int r = 0; r < 2; ++r)
        #pragma unroll
        for (int c = 0; c < 32; ++c) y1[r][c] = 0.f;

    // ---- prologue: tiles 0 and 1 in flight
    stageMain(x0, 0, &lds[0]);     stageX1(0, &lds[0]);
    stageMain(x0, 1, &lds[6144]);  stageX1(1, &lds[6144]);
    asm volatile("s_waitcnt vmcnt(24)" ::: "memory");   // tile 0 landed
    __builtin_amdgcn_s_barrier();

    // ---- phase 1: b-tiles 0..7
    #pragma unroll 1
    for (int t = 0; t < 8; ++t) {
        const float* bb  = &lds[(t & 1) * 6144];
        const float* x1b = bb + 4096;
        #pragma unroll
        for (int bl = 0; bl < 4; ++bl) {
            float xa = x1b[((ag * 2 + 0) * 4 + bl) * 32 + zl];
            float xb = x1b[((ag * 2 + 1) * 4 + bl) * 32 + zl];
            #pragma unroll
            for (int c4 = 0; c4 < 8; ++c4) {
                float4 s = *reinterpret_cast<const float4*>(
                    &bb[((bl * 8 + c4) * 32 + zl) * 4]);
                y1[0][c4 * 4 + 0] = fmaf(xa, s.x, y1[0][c4 * 4 + 0]);
                y1[0][c4 * 4 + 1] = fmaf(xa, s.y, y1[0][c4 * 4 + 1]);
                y1[0][c4 * 4 + 2] = fmaf(xa, s.z, y1[0][c4 * 4 + 2]);
                y1[0][c4 * 4 + 3] = fmaf(xa, s.w, y1[0][c4 * 4 + 3]);
                y1[1][c4 * 4 + 0] = fmaf(xb, s.x, y1[1][c4 * 4 + 0]);
                y1[1][c4 * 4 + 1] = fmaf(xb, s.y, y1[1][c4 * 4 + 1]);
                y1[1][c4 * 4 + 2] = fmaf(xb, s.z, y1[1][c4 * 4 + 2]);
                y1[1][c4 * 4 + 3] = fmaf(xb, s.w, y1[1][c4 * 4 + 3]);
            }
        }

        asm volatile("" ::: "memory");
        __builtin_amdgcn_s_barrier();          // readers done with this buffer

        const int s = t + 2;
        float* nb = &lds[(s & 1) * 6144];      // same parity as just-computed buf
        if (s < 8) { stageMain(x0, s, nb); stageX1(s, nb); }
        else       { stageMain(x2, s - 8, nb); }
        if (t < 6) asm volatile("s_waitcnt vmcnt(24)" ::: "memory");  // tile t+1 landed
        else       asm volatile("s_waitcnt vmcnt(16)" ::: "memory");
        __builtin_amdgcn_s_barrier();
    }

    // ---- phase 2: c-tiles 0..7 (unrolled: y1 index static)
    float y2[2][32];
    #pragma unroll
    for (int r = 0; r < 2; ++r)
        #pragma unroll
        for (int d = 0; d < 32; ++d) y2[r][d] = 0.f;

    #pragma unroll
    for (int u = 0; u < 8; ++u) {
        const float* bb = &lds[(u & 1) * 6144];
        #pragma unroll
        for (int cl = 0; cl < 4; ++cl) {
            const float wa = y1[0][u * 4 + cl];
            const float wb = y1[1][u * 4 + cl];
            #pragma unroll
            for (int d4 = 0; d4 < 8; ++d4) {
                float4 s = *reinterpret_cast<const float4*>(
                    &bb[((cl * 8 + d4) * 32 + zl) * 4]);
                y2[0][d4 * 4 + 0] = fmaf(wa, s.x, y2[0][d4 * 4 + 0]);
                y2[0][d4 * 4 + 1] = fmaf(wa, s.y, y2[0][d4 * 4 + 1]);
                y2[0][d4 * 4 + 2] = fmaf(wa, s.z, y2[0][d4 * 4 + 2]);
                y2[0][d4 * 4 + 3] = fmaf(wa, s.w, y2[0][d4 * 4 + 3]);
                y2[1][d4 * 4 + 0] = fmaf(wb, s.x, y2[1][d4 * 4 + 0]);
                y2[1][d4 * 4 + 1] = fmaf(wb, s.y, y2[1][d4 * 4 + 1]);
                y2[1][d4 * 4 + 2] = fmaf(wb, s.z, y2[1][d4 * 4 + 2]);
                y2[1][d4 * 4 + 3] = fmaf(wb, s.w, y2[1][d4 * 4 + 3]);
            }
        }

        asm volatile("" ::: "memory");
        if (u < 6) {
            __builtin_amdgcn_s_barrier();                  // readers done
            stageMain(x2, u + 2, &lds[(u & 1) * 6144]);    // overwrite with tile u+2
            asm volatile("s_waitcnt vmcnt(16)" ::: "memory");  // tile u+1 landed
            __builtin_amdgcn_s_barrier();
        } else if (u == 6) {
            asm volatile("s_waitcnt vmcnt(0)" ::: "memory");   // last tile landed
            __builtin_amdgcn_s_barrier();
        }
    }

    // ---- store: 128 B segments per (a,d) row
    const int a0 = ahalf * 16 + ag * 2;
    #pragma unroll
    for (int r = 0; r < 2; ++r) {
        #pragma unroll
        for (int d = 0; d < 32; ++d)
            out[(size_t)((a0 + r) * 32 + d) * ZTL + z0 + zl] = y2[r][d];
    }
}

extern "C" void kernel_launch(void* const* d_in, const int* in_sizes, int n_in,
                              void* d_out, int out_size, void* d_ws, size_t ws_size,
                              hipStream_t stream) {
    const float* x0 = (const float*)d_in[0];  // (b,c,Z)
    const float* x1 = (const float*)d_in[1];  // (a,b,Z)
    const float* x2 = (const float*)d_in[2];  // (c,d,Z)
    float* out = (float*)d_out;

    dim3 grid(2048);   // 1024 z-chunks x 2 a-halves
    dim3 block(THREADS);
    hipLaunchKernelGGL(einnet_kernel, grid, block, 0, stream, x0, x1, x2, out);
}

// Round 5
// 249.061 us; speedup vs baseline: 2.3826x; 1.9509x over previous
//
#include <hip/hip_runtime.h>

#define ZT 32768
#define ZTL ((size_t)ZT)
#define THREADS 256

// y2[a,d,z] = sum_b x1[a,b,z] * ( sum_c x0[b,c,z] * x2[c,d,z] )   (associativity)
//
// Block = one (z-chunk of 32) x (d-quarter of 8). 256 threads = 32 z x 8 groups.
// Phase A: T[b, d0..d0+8, z] = X0.X2 slice; thread owns 4 b-rows x 8 d (32 acc).
//          x2 slice staged in 4-c-tile ping-pong (2x4 KB); x0 streamed to regs.
//          T written to LDS (32 KB), registers freed.
// Phase B: y2[a, d0..d0+8, z] = X1.T; thread owns 4 a-rows x 8 d (32 acc).
//          T read from LDS (half-wave broadcast float4), x1 streamed to regs.
// Max live ~= 32 acc + 16 prefetch -> ~100 VGPR, no spill. LDS 40 KB -> 4 blk/CU.
__global__ __launch_bounds__(THREADS, 4) void einnet_kernel(
    const float* __restrict__ x0,   // (b,c,Z)
    const float* __restrict__ x1,   // (a,b,Z)
    const float* __restrict__ x2,   // (c,d,Z)
    float* __restrict__ out)        // (a,d,Z)
{
    // [0..2047]: x2 ping-pong (2 x 1024 floats); [2048..10239]: T (8192 floats)
    __shared__ float lds[10240];

    const int tid = threadIdx.x;
    const int bid = blockIdx.x;
    const int zc  = ((bid >> 5) << 3) | (bid & 7);   // 4 same-z blocks -> same XCD
    const int dq  = (bid >> 3) & 3;
    const int z0  = zc * 32;
    const int d0  = dq * 8;
    const int zl  = tid & 31;
    const int grp = tid >> 5;          // 0..7

    // ---- x2 gather slot: one float4 per tile per thread
    const int s_cl = tid >> 6;         // 0..3  c within tile
    const int s_d4 = (tid >> 5) & 1;   // 0..1  d-float4
    const int s_zs = tid & 31;
    const float* x2g = x2 + (size_t)(s_cl * 32 + d0 + s_d4 * 4) * ZTL + z0 + s_zs;
    const int s_w = ((s_cl * 2 + s_d4) * 32 + s_zs) * 4;   // lds word in buf

    // =================== phase A: T = X0 . X2 (d-slice) ===================
    float Ta[4][8];
    #pragma unroll
    for (int b = 0; b < 4; ++b)
        #pragma unroll
        for (int d = 0; d < 8; ++d) Ta[b][d] = 0.f;

    float xf[4][4], xn[4][4];
    float4 v;

    const float* x0b = x0 + (size_t)(grp * 4) * 32 * ZTL + z0 + zl;  // b=4grp, c=0

    // prologue: tile 0
    v.x = x2g[0]; v.y = x2g[ZTL]; v.z = x2g[2 * ZTL]; v.w = x2g[3 * ZTL];
    #pragma unroll
    for (int bb = 0; bb < 4; ++bb)
        #pragma unroll
        for (int cl = 0; cl < 4; ++cl)
            xf[bb][cl] = x0b[(size_t)(bb * 32 + cl) * ZTL];
    *reinterpret_cast<float4*>(&lds[s_w]) = v;
    __syncthreads();

    #pragma unroll 1
    for (int t = 0; t < 8; ++t) {
        if (t < 7) {   // issue next tile's global loads first (latency hides under compute)
            const float* g = x2g + (size_t)((t + 1) * 128) * ZTL;
            v.x = g[0]; v.y = g[ZTL]; v.z = g[2 * ZTL]; v.w = g[3 * ZTL];
            #pragma unroll
            for (int bb = 0; bb < 4; ++bb)
                #pragma unroll
                for (int cl = 0; cl < 4; ++cl)
                    xn[bb][cl] = x0b[(size_t)(bb * 32 + (t + 1) * 4 + cl) * ZTL];
        }

        const float* buf = &lds[(t & 1) * 1024];
        #pragma unroll
        for (int cl = 0; cl < 4; ++cl) {
            #pragma unroll
            for (int d4 = 0; d4 < 2; ++d4) {
                float4 s = *reinterpret_cast<const float4*>(
                    &buf[((cl * 2 + d4) * 32 + zl) * 4]);
                #pragma unroll
                for (int bb = 0; bb < 4; ++bb) {
                    Ta[bb][d4 * 4 + 0] = fmaf(xf[bb][cl], s.x, Ta[bb][d4 * 4 + 0]);
                    Ta[bb][d4 * 4 + 1] = fmaf(xf[bb][cl], s.y, Ta[bb][d4 * 4 + 1]);
                    Ta[bb][d4 * 4 + 2] = fmaf(xf[bb][cl], s.z, Ta[bb][d4 * 4 + 2]);
                    Ta[bb][d4 * 4 + 3] = fmaf(xf[bb][cl], s.w, Ta[bb][d4 * 4 + 3]);
                }
            }
        }

        if (t < 7) {
            *reinterpret_cast<float4*>(&lds[((t + 1) & 1) * 1024 + s_w]) = v;
            #pragma unroll
            for (int bb = 0; bb < 4; ++bb)
                #pragma unroll
                for (int cl = 0; cl < 4; ++cl)
                    xf[bb][cl] = xn[bb][cl];
        }
        __syncthreads();
    }

    // =================== transition: x1 prefetch, T -> LDS ===================
    float xa[4][4], xb[4][4];
    const float* x1b = x1 + (size_t)(grp * 4) * 32 * ZTL + z0 + zl;  // a=4grp, b=0
    #pragma unroll
    for (int aa = 0; aa < 4; ++aa)
        #pragma unroll
        for (int bl = 0; bl < 4; ++bl)
            xa[aa][bl] = x1b[(size_t)(aa * 32 + bl) * ZTL];

    #pragma unroll
    for (int bb = 0; bb < 4; ++bb) {
        #pragma unroll
        for (int d4 = 0; d4 < 2; ++d4) {
            float4 w;
            w.x = Ta[bb][d4 * 4 + 0]; w.y = Ta[bb][d4 * 4 + 1];
            w.z = Ta[bb][d4 * 4 + 2]; w.w = Ta[bb][d4 * 4 + 3];
            *reinterpret_cast<float4*>(
                &lds[2048 + (((grp * 4 + bb) * 2 + d4) * 32 + zl) * 4]) = w;
        }
    }
    __syncthreads();

    // =================== phase B: y2 = X1 . T ===================
    float y2[4][8];
    #pragma unroll
    for (int a = 0; a < 4; ++a)
        #pragma unroll
        for (int d = 0; d < 8; ++d) y2[a][d] = 0.f;

    #pragma unroll
    for (int u = 0; u < 8; ++u) {
        if (u < 7) {
            #pragma unroll
            for (int aa = 0; aa < 4; ++aa)
                #pragma unroll
                for (int bl = 0; bl < 4; ++bl)
                    xb[aa][bl] = x1b[(size_t)(aa * 32 + (u + 1) * 4 + bl) * ZTL];
        }

        #pragma unroll
        for (int bl = 0; bl < 4; ++bl) {
            #pragma unroll
            for (int d4 = 0; d4 < 2; ++d4) {
                float4 s = *reinterpret_cast<const float4*>(
                    &lds[2048 + (((u * 4 + bl) * 2 + d4) * 32 + zl) * 4]);
                #pragma unroll
                for (int aa = 0; aa < 4; ++aa) {
                    y2[aa][d4 * 4 + 0] = fmaf(xa[aa][bl], s.x, y2[aa][d4 * 4 + 0]);
                    y2[aa][d4 * 4 + 1] = fmaf(xa[aa][bl], s.y, y2[aa][d4 * 4 + 1]);
                    y2[aa][d4 * 4 + 2] = fmaf(xa[aa][bl], s.z, y2[aa][d4 * 4 + 2]);
                    y2[aa][d4 * 4 + 3] = fmaf(xa[aa][bl], s.w, y2[aa][d4 * 4 + 3]);
                }
            }
        }

        if (u < 7) {
            #pragma unroll
            for (int aa = 0; aa < 4; ++aa)
                #pragma unroll
                for (int bl = 0; bl < 4; ++bl)
                    xa[aa][bl] = xb[aa][bl];
        }
    }

    // ---- store: 128 B segments per (a,d) row
    #pragma unroll
    for (int aa = 0; aa < 4; ++aa)
        #pragma unroll
        for (int dd = 0; dd < 8; ++dd)
            out[(size_t)((grp * 4 + aa) * 32 + d0 + dd) * ZTL + z0 + zl] = y2[aa][dd];
}

extern "C" void kernel_launch(void* const* d_in, const int* in_sizes, int n_in,
                              void* d_out, int out_size, void* d_ws, size_t ws_size,
                              hipStream_t stream) {
    const float* x0 = (const float*)d_in[0];  // (b,c,Z)
    const float* x1 = (const float*)d_in[1];  // (a,b,Z)
    const float* x2 = (const float*)d_in[2];  // (c,d,Z)
    float* out = (float*)d_out;

    dim3 grid(4096);   // 1024 z-chunks x 4 d-quarters
    dim3 block(THREADS);
    hipLaunchKernelGGL(einnet_kernel, grid, block, 0, stream, x0, x1, x2, out);
}